// Round 1
// baseline (221.849 us; speedup 1.0000x reference)
//
#include <hip/hip_runtime.h>

// Problem: x [32,3,512,512] f32, colors [20,3] f32.
// out = mean over pixels of sqrt(min_c |p - c|^2).
// Algebra: |p-c|^2 = |p|^2 + (|c|^2 - 2 p.c); min over c of the paren term,
// then add |p|^2 once. Per color: 3 FMA + 1 min.

#define HW_   (512 * 512)          // 262144 (power of two: 2^18)
#define NPIX_ (32 * HW_)           // 8388608 pixels
#define NCOL_ 20
#define PIX_PER_THREAD 4
#define BLOCK_ 256
#define NBLOCKS_ (NPIX_ / PIX_PER_THREAD / BLOCK_)   // 8192, exact, no tail

__global__ __launch_bounds__(BLOCK_) void nps_main(
    const float* __restrict__ x,
    const float* __restrict__ colors,
    float* __restrict__ ws_sum) {

  __shared__ float4 ccol[NCOL_];   // (-2cx, -2cy, -2cz, |c|^2)
  __shared__ float wsum[BLOCK_ / 64];

  const int tid = threadIdx.x;
  if (tid < NCOL_) {
    float cx = colors[tid * 3 + 0];
    float cy = colors[tid * 3 + 1];
    float cz = colors[tid * 3 + 2];
    ccol[tid] = make_float4(-2.0f * cx, -2.0f * cy, -2.0f * cz,
                            cx * cx + cy * cy + cz * cz);
  }
  __syncthreads();

  const int t  = blockIdx.x * BLOCK_ + tid;   // global thread id
  const int p0 = t * PIX_PER_THREAD;          // first pixel (fits in int)
  const int b  = p0 >> 18;                    // p0 / HW_
  const int hw = p0 & (HW_ - 1);              // p0 % HW_

  const float* base = x + (size_t)(b * 3) * HW_ + hw;
  const float4 r  = *(const float4*)(base);
  const float4 g  = *(const float4*)(base + HW_);
  const float4 bl = *(const float4*)(base + 2 * HW_);

  float px[4] = {r.x, r.y, r.z, r.w};
  float py[4] = {g.x, g.y, g.z, g.w};
  float pz[4] = {bl.x, bl.y, bl.z, bl.w};

  float m[4] = {1e30f, 1e30f, 1e30f, 1e30f};
#pragma unroll
  for (int j = 0; j < NCOL_; ++j) {
    const float4 c = ccol[j];
#pragma unroll
    for (int k = 0; k < 4; ++k) {
      float d = fmaf(c.x, px[k], fmaf(c.y, py[k], fmaf(c.z, pz[k], c.w)));
      m[k] = fminf(m[k], d);
    }
  }

  float local = 0.0f;
#pragma unroll
  for (int k = 0; k < 4; ++k) {
    float n2 = fmaf(px[k], px[k], fmaf(py[k], py[k], pz[k] * pz[k]));
    float d2 = fmaxf(m[k] + n2, 0.0f);   // clamp tiny negative from cancellation
    local += sqrtf(d2);
  }

  // wave-64 reduction
#pragma unroll
  for (int off = 32; off > 0; off >>= 1)
    local += __shfl_down(local, off, 64);

  const int wave = tid >> 6;
  if ((tid & 63) == 0) wsum[wave] = local;
  __syncthreads();

  if (tid == 0) {
    float s = 0.0f;
#pragma unroll
    for (int w = 0; w < BLOCK_ / 64; ++w) s += wsum[w];
    atomicAdd(ws_sum, s);
  }
}

__global__ void nps_final(const float* __restrict__ ws_sum,
                          float* __restrict__ out) {
  out[0] = ws_sum[0] * (1.0f / (float)NPIX_);
}

extern "C" void kernel_launch(void* const* d_in, const int* in_sizes, int n_in,
                              void* d_out, int out_size, void* d_ws, size_t ws_size,
                              hipStream_t stream) {
  const float* x      = (const float*)d_in[0];   // 32*3*512*512 f32
  const float* colors = (const float*)d_in[1];   // 20*3 f32
  float* out          = (float*)d_out;           // 1 f32
  float* ws_sum       = (float*)d_ws;            // 4 bytes scratch

  // d_ws is re-poisoned to 0xAA before every timed launch — zero it each call.
  hipMemsetAsync(ws_sum, 0, sizeof(float), stream);

  nps_main<<<NBLOCKS_, BLOCK_, 0, stream>>>(x, colors, ws_sum);
  nps_final<<<1, 1, 0, stream>>>(ws_sum, out);
}

// Round 2
// 145.594 us; speedup vs baseline: 1.5237x; 1.5237x over previous
//
#include <hip/hip_runtime.h>

// x [32,3,512,512] f32, colors [20,3] f32.
// out = mean over pixels of sqrt(min_c |p - c|^2).
// |p-c|^2 = |p|^2 + (|c|^2 - 2 p.c); min over c of paren term, add |p|^2 once.
//
// R1: no atomics (8192 same-address atomicAdds serialized ~100us in R0),
// no memset node. Block partials -> d_ws, second kernel reduces.

#define HW_    (512 * 512)           // 2^18
#define NPIX_  (32 * HW_)            // 8388608
#define NCOL_  20
#define BLOCK_ 256
#define PIX_PER_BLOCK_ 4096          // 16 px/thread, 4 chunks of float4
#define NBLOCKS_ (NPIX_ / PIX_PER_BLOCK_)   // 2048, exact
#define CHUNKS_ 4

__global__ __launch_bounds__(BLOCK_) void nps_main(
    const float* __restrict__ x,
    const float* __restrict__ colors,
    float* __restrict__ partials) {

  __shared__ float4 ccol[NCOL_];   // (-2cx, -2cy, -2cz, |c|^2)
  __shared__ float wsum[BLOCK_ / 64];

  const int tid = threadIdx.x;
  if (tid < NCOL_) {
    float cx = colors[tid * 3 + 0];
    float cy = colors[tid * 3 + 1];
    float cz = colors[tid * 3 + 2];
    ccol[tid] = make_float4(-2.0f * cx, -2.0f * cy, -2.0f * cz,
                            cx * cx + cy * cy + cz * cz);
  }
  __syncthreads();

  // Block tile: PIX_PER_BLOCK_ consecutive pixels, within one image
  // (4096 divides HW_). Chunk c: pixel = tile + c*1024 + tid*4 — every
  // float4 load is perfectly coalesced (lane i at byte 16*i).
  const int tile = blockIdx.x * PIX_PER_BLOCK_;
  const int bimg = tile >> 18;            // tile / HW_
  const int hw   = tile & (HW_ - 1);      // tile % HW_
  const float* base = x + (size_t)(bimg * 3) * HW_ + hw;

  float local = 0.0f;

#pragma unroll
  for (int c = 0; c < CHUNKS_; ++c) {
    const int off = c * (BLOCK_ * 4) + tid * 4;
    const float4 r  = *(const float4*)(base + off);
    const float4 g  = *(const float4*)(base + off + HW_);
    const float4 bl = *(const float4*)(base + off + 2 * HW_);

    const float px[4] = {r.x, r.y, r.z, r.w};
    const float py[4] = {g.x, g.y, g.z, g.w};
    const float pz[4] = {bl.x, bl.y, bl.z, bl.w};

    float m[4] = {1e30f, 1e30f, 1e30f, 1e30f};
#pragma unroll
    for (int j = 0; j < NCOL_; ++j) {
      const float4 cc = ccol[j];
#pragma unroll
      for (int k = 0; k < 4; ++k) {
        float d = fmaf(cc.x, px[k], fmaf(cc.y, py[k], fmaf(cc.z, pz[k], cc.w)));
        m[k] = fminf(m[k], d);
      }
    }
#pragma unroll
    for (int k = 0; k < 4; ++k) {
      float n2 = fmaf(px[k], px[k], fmaf(py[k], py[k], pz[k] * pz[k]));
      float d2 = fmaxf(m[k] + n2, 0.0f);  // clamp cancellation negatives
      local += __builtin_amdgcn_sqrtf(d2);
    }
  }

  // wave-64 reduce, then cross-wave via LDS
#pragma unroll
  for (int off = 32; off > 0; off >>= 1)
    local += __shfl_down(local, off, 64);

  if ((tid & 63) == 0) wsum[tid >> 6] = local;
  __syncthreads();

  if (tid == 0) {
    float s = 0.0f;
#pragma unroll
    for (int w = 0; w < BLOCK_ / 64; ++w) s += wsum[w];
    partials[blockIdx.x] = s;
  }
}

__global__ __launch_bounds__(BLOCK_) void nps_reduce(
    const float* __restrict__ partials,
    float* __restrict__ out) {
  __shared__ float wsum[BLOCK_ / 64];
  const int tid = threadIdx.x;

  float local = 0.0f;
#pragma unroll
  for (int i = 0; i < NBLOCKS_ / BLOCK_; ++i)   // 8 each
    local += partials[i * BLOCK_ + tid];

#pragma unroll
  for (int off = 32; off > 0; off >>= 1)
    local += __shfl_down(local, off, 64);

  if ((tid & 63) == 0) wsum[tid >> 6] = local;
  __syncthreads();

  if (tid == 0) {
    float s = 0.0f;
#pragma unroll
    for (int w = 0; w < BLOCK_ / 64; ++w) s += wsum[w];
    out[0] = s * (1.0f / (float)NPIX_);
  }
}

extern "C" void kernel_launch(void* const* d_in, const int* in_sizes, int n_in,
                              void* d_out, int out_size, void* d_ws, size_t ws_size,
                              hipStream_t stream) {
  const float* x      = (const float*)d_in[0];
  const float* colors = (const float*)d_in[1];
  float* out          = (float*)d_out;
  float* partials     = (float*)d_ws;    // NBLOCKS_ floats, fully overwritten

  nps_main<<<NBLOCKS_, BLOCK_, 0, stream>>>(x, colors, partials);
  nps_reduce<<<1, BLOCK_, 0, stream>>>(partials, out);
}